// Round 2
// baseline (59.567 us; speedup 1.0000x reference)
//
#include <hip/hip_runtime.h>

#define MARGIN 500.0f

// Single-block, single-node graph: no memset, no atomics.
// 1024 threads = 16 waves on one CU; 512 KB input via L2 ~ 3.5 us.
__global__ __launch_bounds__(1024) void custom_loss_onepass(
        const int* __restrict__ labels,
        const float* __restrict__ coords,
        float* __restrict__ out, int N) {
    const int t = threadIdx.x;

    // Anchor = last element (uniform scalar loads).
    const int   anchor_lab = labels[N - 1];
    const float ax = coords[3 * (N - 1) + 0];
    const float ay = coords[3 * (N - 1) + 1];
    const float az = coords[3 * (N - 1) + 2];

    const float4* __restrict__ c4 = (const float4*)coords;  // 3 float4 per 4 elems
    const int4*   __restrict__ l4 = (const int4*)labels;    // 1 int4  per 4 elems

    const int ngroups = N >> 2;  // 8192 groups of 4 elements
    float v = 0.0f;
    for (int g = t; g < ngroups; g += 1024) {
        const float4 p0 = c4[3 * g + 0];
        const float4 p1 = c4[3 * g + 1];
        const float4 p2 = c4[3 * g + 2];
        const int4   lb = l4[g];
        // e0=(p0.x,p0.y,p0.z) e1=(p0.w,p1.x,p1.y) e2=(p1.z,p1.w,p2.x) e3=(p2.y,p2.z,p2.w)
        {
            const float dx = ax - p0.x, dy = ay - p0.y, dz = az - p0.z;
            const float d = dx * dx + dy * dy + dz * dz;
            v += (lb.x == anchor_lab) ? d : fmaxf(0.0f, MARGIN - d);
        }
        {
            const float dx = ax - p0.w, dy = ay - p1.x, dz = az - p1.y;
            const float d = dx * dx + dy * dy + dz * dz;
            v += (lb.y == anchor_lab) ? d : fmaxf(0.0f, MARGIN - d);
        }
        {
            const float dx = ax - p1.z, dy = ay - p1.w, dz = az - p2.x;
            const float d = dx * dx + dy * dy + dz * dz;
            v += (lb.z == anchor_lab) ? d : fmaxf(0.0f, MARGIN - d);
        }
        {
            const float dx = ax - p2.y, dy = ay - p2.z, dz = az - p2.w;
            const float d = dx * dx + dy * dy + dz * dz;
            v += (lb.w == anchor_lab) ? d : fmaxf(0.0f, MARGIN - d);
        }
    }

    // Wave-64 butterfly, then cross-wave via LDS.
    #pragma unroll
    for (int off = 32; off > 0; off >>= 1)
        v += __shfl_down(v, off, 64);

    __shared__ float smem[16];
    const int wave = t >> 6;
    const int lane = t & 63;
    if (lane == 0) smem[wave] = v;
    __syncthreads();

    if (t == 0) {
        float s = 0.0f;
        #pragma unroll
        for (int i = 0; i < 16; ++i) s += smem[i];
        out[0] = s;  // plain store: fully overwrites poisoned d_out
    }
}

extern "C" void kernel_launch(void* const* d_in, const int* in_sizes, int n_in,
                              void* d_out, int out_size, void* d_ws, size_t ws_size,
                              hipStream_t stream) {
    const int*   labels = (const int*)d_in[0];
    const float* coords = (const float*)d_in[1];
    float*       out    = (float*)d_out;
    const int N = in_sizes[0];  // 32768, divisible by 4

    custom_loss_onepass<<<1, 1024, 0, stream>>>(labels, coords, out, N);
}

// Round 3
// 57.180 us; speedup vs baseline: 1.0418x; 1.0418x over previous
//
#include <hip/hip_runtime.h>

#define MARGIN 500.0f

// Kernel A: 32 blocks x 256 threads; each thread handles one group of 4
// elements (3 float4 coord loads + 1 int4 label load, fully coalesced).
// Per-block partial -> plain store into d_ws (no init required).
__global__ __launch_bounds__(256) void loss_partial(
        const int* __restrict__ labels,
        const float* __restrict__ coords,
        float* __restrict__ partial, int N) {
    const int   anchor_lab = labels[N - 1];
    const float ax = coords[3 * (N - 1) + 0];
    const float ay = coords[3 * (N - 1) + 1];
    const float az = coords[3 * (N - 1) + 2];

    const float4* __restrict__ c4 = (const float4*)coords;
    const int4*   __restrict__ l4 = (const int4*)labels;

    const int g = blockIdx.x * blockDim.x + threadIdx.x;  // 8192 groups total
    float v = 0.0f;
    if (g < (N >> 2)) {
        const float4 p0 = c4[3 * g + 0];
        const float4 p1 = c4[3 * g + 1];
        const float4 p2 = c4[3 * g + 2];
        const int4   lb = l4[g];
        // e0=(p0.x,p0.y,p0.z) e1=(p0.w,p1.x,p1.y) e2=(p1.z,p1.w,p2.x) e3=(p2.y,p2.z,p2.w)
        {
            const float dx = ax - p0.x, dy = ay - p0.y, dz = az - p0.z;
            const float d = dx * dx + dy * dy + dz * dz;
            v += (lb.x == anchor_lab) ? d : fmaxf(0.0f, MARGIN - d);
        }
        {
            const float dx = ax - p0.w, dy = ay - p1.x, dz = az - p1.y;
            const float d = dx * dx + dy * dy + dz * dz;
            v += (lb.y == anchor_lab) ? d : fmaxf(0.0f, MARGIN - d);
        }
        {
            const float dx = ax - p1.z, dy = ay - p1.w, dz = az - p2.x;
            const float d = dx * dx + dy * dy + dz * dz;
            v += (lb.z == anchor_lab) ? d : fmaxf(0.0f, MARGIN - d);
        }
        {
            const float dx = ax - p2.y, dy = ay - p2.z, dz = az - p2.w;
            const float d = dx * dx + dy * dy + dz * dz;
            v += (lb.w == anchor_lab) ? d : fmaxf(0.0f, MARGIN - d);
        }
    }

    #pragma unroll
    for (int off = 32; off > 0; off >>= 1)
        v += __shfl_down(v, off, 64);

    __shared__ float smem[4];
    const int wave = threadIdx.x >> 6;
    const int lane = threadIdx.x & 63;
    if (lane == 0) smem[wave] = v;
    __syncthreads();

    if (threadIdx.x == 0)
        partial[blockIdx.x] = smem[0] + smem[1] + smem[2] + smem[3];
}

// Kernel B: one wave reduces the 32 partials.
__global__ __launch_bounds__(64) void loss_final(
        const float* __restrict__ partial, float* __restrict__ out, int nparts) {
    const int lane = threadIdx.x;
    float v = (lane < nparts) ? partial[lane] : 0.0f;
    #pragma unroll
    for (int off = 32; off > 0; off >>= 1)
        v += __shfl_down(v, off, 64);
    if (lane == 0) out[0] = v;  // plain store over poisoned d_out
}

extern "C" void kernel_launch(void* const* d_in, const int* in_sizes, int n_in,
                              void* d_out, int out_size, void* d_ws, size_t ws_size,
                              hipStream_t stream) {
    const int*   labels = (const int*)d_in[0];
    const float* coords = (const float*)d_in[1];
    float*       out    = (float*)d_out;
    float*       partial = (float*)d_ws;
    const int N = in_sizes[0];  // 32768

    const int block = 256;
    const int grid  = (N / 4 + block - 1) / block;  // 32 blocks
    loss_partial<<<grid, block, 0, stream>>>(labels, coords, partial, N);
    loss_final<<<1, 64, 0, stream>>>(partial, out, grid);
}